// Round 4
// baseline (69.972 us; speedup 1.0000x reference)
//
#include <hip/hip_runtime.h>
#include <math.h>

#define THREADS 256
#define PPT 4  // pixels per thread

__device__ __forceinline__ float frcp(float x)  { return __builtin_amdgcn_rcpf(x); }
__device__ __forceinline__ float fsqrt(float x) { return __builtin_amdgcn_sqrtf(x); }

__device__ __forceinline__ float fast_sigmoid(float x) {
    return frcp(1.0f + __expf(-x));
}

// skimage-style rgb2hsv, H and V only
__device__ __forceinline__ void rgb2hv(float r, float g, float b,
                                       float& h, float& v) {
    float maxc = fmaxf(r, fmaxf(g, b));
    float minc = fminf(r, fminf(g, b));
    float delta = maxc - minc;
    float rd = frcp((delta == 0.0f) ? 1.0f : delta);
    float hh;
    if (maxc == r)      hh = (g - b) * rd;
    else if (maxc == g) hh = 2.0f + (b - r) * rd;
    else                hh = 4.0f + (r - g) * rd;
    hh = hh * (1.0f / 6.0f);
    hh = hh - floorf(hh);          // (h/6) mod 1.0
    h = (delta == 0.0f) ? 0.0f : hh;
    v = maxc;
}

__device__ __forceinline__ float pixel_loss(
    float gr, float gg, float gb,
    float br, float bgc, float bb,
    float fr, float fgc, float fb,
    float u, float threshold, int it)
{
    if (it > 300) {
        float hg, vg, hb, vb;
        rgb2hv(gr, gg, gb, hg, vg);
        rgb2hv(br, bgc, bb, hb, vb);
        float dh = hg - hb;
        float dv = vg - vb;
        float diff = fsqrt(dh * dh + dv * dv);
        float mask = fast_sigmoid((diff - threshold) * 10.0f);

        float d0 = gr - br, d1 = gg - bgc, d2 = gb - bb;
        float bg_mse = (d0 * d0 + d1 * d1 + d2 * d2) * (1.0f / 3.0f);

        float e0 = gr - fr, e1 = gg - fgc, e2 = gb - fb;
        float fg_mse = (e0 * e0 + e1 * e1 + e2 * e2) * (1.0f / 3.0f);
        float fg_perray = fg_mse * 0.5f * frcp(u * u) + __logf(u);

        return bg_mse + (fg_perray - bg_mse) * mask;
    } else {
        float d0 = gr - br, d1 = gg - bgc, d2 = gb - bb;
        return d0 * d0 + d1 * d1 + d2 * d2;  // denom = 3N in this branch
    }
}

__global__ __launch_bounds__(THREADS) void loss_kernel(
    const float* __restrict__ gt, const float* __restrict__ bg,
    const float* __restrict__ fg, const float* __restrict__ unc,
    const float* __restrict__ thr_param, const int* __restrict__ iter_p,
    float* __restrict__ out, int n_pix)
{
    const int t = blockIdx.x * blockDim.x + threadIdx.x;
    const int p0 = t * PPT;
    const int it = iter_p[0];
    const float threshold = 1.414f * (1.0f - fast_sigmoid(thr_param[0]));

    float local = 0.0f;

    if (p0 + PPT <= n_pix) {
        const float4* g4 = (const float4*)gt + 3 * t;
        const float4* b4 = (const float4*)bg + 3 * t;
        const float4* f4 = (const float4*)fg + 3 * t;
        float4 ga = g4[0], gbv = g4[1], gc = g4[2];
        float4 ba = b4[0], bbv = b4[1], bc = b4[2];
        float4 fa = f4[0], fbv = f4[1], fc = f4[2];
        float4 u4 = *(const float4*)(unc + p0);

        float G[12] = {ga.x, ga.y, ga.z, ga.w, gbv.x, gbv.y, gbv.z, gbv.w,
                       gc.x, gc.y, gc.z, gc.w};
        float B[12] = {ba.x, ba.y, ba.z, ba.w, bbv.x, bbv.y, bbv.z, bbv.w,
                       bc.x, bc.y, bc.z, bc.w};
        float F[12] = {fa.x, fa.y, fa.z, fa.w, fbv.x, fbv.y, fbv.z, fbv.w,
                       fc.x, fc.y, fc.z, fc.w};
        float U[4] = {u4.x, u4.y, u4.z, u4.w};

        #pragma unroll
        for (int j = 0; j < PPT; ++j) {
            local += pixel_loss(G[3*j], G[3*j+1], G[3*j+2],
                                B[3*j], B[3*j+1], B[3*j+2],
                                F[3*j], F[3*j+1], F[3*j+2],
                                U[j], threshold, it);
        }
    } else if (p0 < n_pix) {
        for (int p = p0; p < n_pix; ++p) {
            local += pixel_loss(gt[3*p], gt[3*p+1], gt[3*p+2],
                                bg[3*p], bg[3*p+1], bg[3*p+2],
                                fg[3*p], fg[3*p+1], fg[3*p+2],
                                unc[p], threshold, it);
        }
    }

    // 64-lane wave reduce
    #pragma unroll
    for (int off = 32; off > 0; off >>= 1)
        local += __shfl_down(local, off, 64);

    __shared__ double wsum[THREADS / 64];
    const int lane = threadIdx.x & 63;
    const int wid = threadIdx.x >> 6;
    if (lane == 0) wsum[wid] = (double)local;
    __syncthreads();
    if (threadIdx.x == 0) {
        double s = 0.0;
        #pragma unroll
        for (int w = 0; w < THREADS / 64; ++w) s += wsum[w];
        double denom = (it > 300) ? (double)n_pix : 3.0 * (double)n_pix;
        // One staggered same-address f32 atomic per block (2048 total):
        // contention-negligible, overlapped with block retirement.
        atomicAdd(out, (float)(s / denom));
    }
}

extern "C" void kernel_launch(void* const* d_in, const int* in_sizes, int n_in,
                              void* d_out, int out_size, void* d_ws, size_t ws_size,
                              hipStream_t stream) {
    const float* gt  = (const float*)d_in[0];
    const float* bg  = (const float*)d_in[1];
    const float* fg  = (const float*)d_in[2];
    // d_in[3] = FG_acc : unused by reference
    const float* unc = (const float*)d_in[4];   // FG_uncertainties [N,1]
    const float* thr = (const float*)d_in[5];   // threshold_param
    // d_in[6] = steepness : unused (0.1 hard-coded in reference)
    const int*  iter = (const int*)d_in[7];

    const int n_pix = in_sizes[0] / 3;
    const int total_threads = (n_pix + PPT - 1) / PPT;
    const int blocks = (total_threads + THREADS - 1) / THREADS;

    // d_out is not re-zeroed between graph replays by the harness; a 4-byte
    // async memset node (graph-capture safe) zeroes the accumulator.
    hipMemsetAsync(d_out, 0, sizeof(float), stream);

    loss_kernel<<<blocks, THREADS, 0, stream>>>(gt, bg, fg, unc, thr, iter,
                                                (float*)d_out, n_pix);
}

// Round 5
// 35.129 us; speedup vs baseline: 1.9918x; 1.9918x over previous
//
#include <hip/hip_runtime.h>
#include <math.h>

#define THREADS 256
#define ITERS 4   // pixels per thread via grid-stride; blocks = N/(256*4) = 4096

__device__ __forceinline__ float frcp(float x)  { return __builtin_amdgcn_rcpf(x); }
__device__ __forceinline__ float fsqrt(float x) { return __builtin_amdgcn_sqrtf(x); }

__device__ __forceinline__ float fast_sigmoid(float x) {
    return frcp(1.0f + __expf(-x));
}

// skimage-style rgb2hsv, H and V only
__device__ __forceinline__ void rgb2hv(float r, float g, float b,
                                       float& h, float& v) {
    float maxc = fmaxf(r, fmaxf(g, b));
    float minc = fminf(r, fminf(g, b));
    float delta = maxc - minc;
    float rd = frcp((delta == 0.0f) ? 1.0f : delta);
    float hh;
    if (maxc == r)      hh = (g - b) * rd;
    else if (maxc == g) hh = 2.0f + (b - r) * rd;
    else                hh = 4.0f + (r - g) * rd;
    hh = hh * (1.0f / 6.0f);
    hh = hh - floorf(hh);          // (h/6) mod 1.0
    h = (delta == 0.0f) ? 0.0f : hh;
    v = maxc;
}

__device__ __forceinline__ float pixel_loss(
    float3 g, float3 b, float3 f, float u, float threshold, int it)
{
    if (it > 300) {
        float hg, vg, hb, vb;
        rgb2hv(g.x, g.y, g.z, hg, vg);
        rgb2hv(b.x, b.y, b.z, hb, vb);
        float dh = hg - hb;
        float dv = vg - vb;
        float diff = fsqrt(dh * dh + dv * dv);
        float mask = fast_sigmoid((diff - threshold) * 10.0f);

        float d0 = g.x - b.x, d1 = g.y - b.y, d2 = g.z - b.z;
        float bg_mse = (d0 * d0 + d1 * d1 + d2 * d2) * (1.0f / 3.0f);

        float e0 = g.x - f.x, e1 = g.y - f.y, e2 = g.z - f.z;
        float fg_mse = (e0 * e0 + e1 * e1 + e2 * e2) * (1.0f / 3.0f);
        float fg_perray = fg_mse * 0.5f * frcp(u * u) + __logf(u);

        return bg_mse + (fg_perray - bg_mse) * mask;
    } else {
        float d0 = g.x - b.x, d1 = g.y - b.y, d2 = g.z - b.z;
        return d0 * d0 + d1 * d1 + d2 * d2;  // denom = 3N in this branch
    }
}

__global__ __launch_bounds__(THREADS) void loss_kernel(
    const float* __restrict__ gt, const float* __restrict__ bg,
    const float* __restrict__ fg, const float* __restrict__ unc,
    const float* __restrict__ thr_param, const int* __restrict__ iter_p,
    double* __restrict__ partials, int n_pix)
{
    const int t0 = blockIdx.x * blockDim.x + threadIdx.x;
    const int stride = gridDim.x * blockDim.x;
    const int it = iter_p[0];
    const float threshold = 1.414f * (1.0f - fast_sigmoid(thr_param[0]));

    // float3 = 12 B: lane i reads [12i, 12i+12) -> every load instruction
    // covers a fully-dense contiguous 768 B span (minimum line-visits/byte),
    // unlike the PPT=4 float4 scheme whose lanes sat 48 B apart.
    const float3* g3 = (const float3*)gt;
    const float3* b3 = (const float3*)bg;
    const float3* f3 = (const float3*)fg;

    float local = 0.0f;

    int P[ITERS];
    #pragma unroll
    for (int k = 0; k < ITERS; ++k) P[k] = t0 + k * stride;

    if (P[ITERS - 1] < n_pix) {
        // fast path (all iterations in range): batch all 16 loads up front
        float3 G[ITERS], B[ITERS], F[ITERS];
        float  U[ITERS];
        #pragma unroll
        for (int k = 0; k < ITERS; ++k) {
            G[k] = g3[P[k]];
            B[k] = b3[P[k]];
            F[k] = f3[P[k]];
            U[k] = unc[P[k]];
        }
        #pragma unroll
        for (int k = 0; k < ITERS; ++k)
            local += pixel_loss(G[k], B[k], F[k], U[k], threshold, it);
    } else {
        #pragma unroll
        for (int k = 0; k < ITERS; ++k)
            if (P[k] < n_pix)
                local += pixel_loss(g3[P[k]], b3[P[k]], f3[P[k]], unc[P[k]],
                                    threshold, it);
    }

    // 64-lane wave reduce
    #pragma unroll
    for (int off = 32; off > 0; off >>= 1)
        local += __shfl_down(local, off, 64);

    __shared__ double wsum[THREADS / 64];
    const int lane = threadIdx.x & 63;
    const int wid = threadIdx.x >> 6;
    if (lane == 0) wsum[wid] = (double)local;
    __syncthreads();
    if (threadIdx.x == 0) {
        double s = 0.0;
        #pragma unroll
        for (int w = 0; w < THREADS / 64; ++w) s += wsum[w];
        partials[blockIdx.x] = s;   // one slot per block, no atomics
    }
}

__global__ __launch_bounds__(1024) void finalize_kernel(
    const double* __restrict__ partials, int n_part,
    const int* __restrict__ iter_p, float* __restrict__ out, int n_pix)
{
    double s = 0.0;
    for (int i = threadIdx.x; i < n_part; i += 1024)
        s += partials[i];
    #pragma unroll
    for (int off = 32; off > 0; off >>= 1)
        s += __shfl_down(s, off, 64);

    __shared__ double wsum[16];
    const int lane = threadIdx.x & 63;
    const int wid = threadIdx.x >> 6;
    if (lane == 0) wsum[wid] = s;
    __syncthreads();
    if (threadIdx.x == 0) {
        double tot = 0.0;
        #pragma unroll
        for (int w = 0; w < 16; ++w) tot += wsum[w];
        double denom = (iter_p[0] > 300) ? (double)n_pix : 3.0 * (double)n_pix;
        out[0] = (float)(tot / denom);
    }
}

extern "C" void kernel_launch(void* const* d_in, const int* in_sizes, int n_in,
                              void* d_out, int out_size, void* d_ws, size_t ws_size,
                              hipStream_t stream) {
    const float* gt  = (const float*)d_in[0];
    const float* bg  = (const float*)d_in[1];
    const float* fg  = (const float*)d_in[2];
    // d_in[3] = FG_acc : unused by reference
    const float* unc = (const float*)d_in[4];   // FG_uncertainties [N,1]
    const float* thr = (const float*)d_in[5];   // threshold_param
    // d_in[6] = steepness : unused (0.1 hard-coded in reference)
    const int*  iter = (const int*)d_in[7];

    const int n_pix = in_sizes[0] / 3;
    int blocks = (n_pix + THREADS * ITERS - 1) / (THREADS * ITERS);

    // cap partials to what ws can hold (grid-stride handles any block count)
    int max_blocks = (int)(ws_size / sizeof(double));
    if (blocks > max_blocks) blocks = max_blocks;

    double* partials = (double*)d_ws;

    loss_kernel<<<blocks, THREADS, 0, stream>>>(gt, bg, fg, unc, thr, iter,
                                                partials, n_pix);
    finalize_kernel<<<1, 1024, 0, stream>>>(partials, blocks, iter,
                                            (float*)d_out, n_pix);
}

// Round 6
// 34.778 us; speedup vs baseline: 2.0120x; 1.0101x over previous
//
#include <hip/hip_runtime.h>
#include <math.h>
#include <stdint.h>

#define THREADS   256
#define CHUNK_PX  512
#define CHUNKS    4
#define BLOCK_PX  (CHUNK_PX * CHUNKS)   // 2048 pixels per block
#define SEG_B     (CHUNK_PX * 12)       // 6144 B per array per chunk
#define BUF_B     (3 * SEG_B)           // 18432 B per buffer (gt|bg|fg)
#define GROUPS    (BUF_B / 16 / 64)     // 18 wave-groups of 64 x 16B units

__device__ __forceinline__ float frcp(float x)  { return __builtin_amdgcn_rcpf(x); }
__device__ __forceinline__ float fsqrt(float x) { return __builtin_amdgcn_sqrtf(x); }
__device__ __forceinline__ float fast_sigmoid(float x) {
    return frcp(1.0f + __expf(-x));
}

// ---- async global->LDS staging (dense: lane i covers bytes [16i,16i+16)) ----
#if __has_builtin(__builtin_amdgcn_global_load_lds)
#define GLDS16(gsrc, ldst)                                                  \
    __builtin_amdgcn_global_load_lds(                                       \
        (const __attribute__((address_space(1))) uint32_t*)(gsrc),          \
        (__attribute__((address_space(3))) uint32_t*)(ldst), 16, 0, 0)
#else
// reg-staged fallback: same dense global pattern, explicit lane offset
#define GLDS16(gsrc, ldst)                                                  \
    do { *(float4*)((char*)(ldst) + (threadIdx.x & 63) * 16) =              \
         *(const float4*)(gsrc); } while (0)
#endif

// skimage-style rgb2hsv, H and V only
__device__ __forceinline__ void rgb2hv(float r, float g, float b,
                                       float& h, float& v) {
    float maxc = fmaxf(r, fmaxf(g, b));
    float minc = fminf(r, fminf(g, b));
    float delta = maxc - minc;
    float rd = frcp((delta == 0.0f) ? 1.0f : delta);
    float hh;
    if (maxc == r)      hh = (g - b) * rd;
    else if (maxc == g) hh = 2.0f + (b - r) * rd;
    else                hh = 4.0f + (r - g) * rd;
    hh = hh * (1.0f / 6.0f);
    hh = hh - floorf(hh);          // (h/6) mod 1.0
    h = (delta == 0.0f) ? 0.0f : hh;
    v = maxc;
}

__device__ __forceinline__ float pixel_loss(
    float gr, float gg, float gb,
    float br, float bgc, float bb,
    float fr, float fgc, float fb,
    float u, float threshold, int it)
{
    if (it > 300) {
        float hg, vg, hb, vb;
        rgb2hv(gr, gg, gb, hg, vg);
        rgb2hv(br, bgc, bb, hb, vb);
        float dh = hg - hb;
        float dv = vg - vb;
        float diff = fsqrt(dh * dh + dv * dv);
        float mask = fast_sigmoid((diff - threshold) * 10.0f);

        float d0 = gr - br, d1 = gg - bgc, d2 = gb - bb;
        float bg_mse = (d0 * d0 + d1 * d1 + d2 * d2) * (1.0f / 3.0f);

        float e0 = gr - fr, e1 = gg - fgc, e2 = gb - fb;
        float fg_mse = (e0 * e0 + e1 * e1 + e2 * e2) * (1.0f / 3.0f);
        float fg_perray = fg_mse * 0.5f * frcp(u * u) + __logf(u);

        return bg_mse + (fg_perray - bg_mse) * mask;
    } else {
        float d0 = gr - br, d1 = gg - bgc, d2 = gb - bb;
        return d0 * d0 + d1 * d1 + d2 * d2;   // denom = 3N in this branch
    }
}

// Stage one 512-pixel chunk (gt|bg|fg = 1152 16B units = 18 wave-groups).
// Groups 0-5: gt, 6-11: bg, 12-17: fg -- each group entirely in one segment.
__device__ __forceinline__ void stage_chunk(
    const float4* __restrict__ g4, const float4* __restrict__ b4,
    const float4* __restrict__ f4, char* buf, int pix0)
{
    const int wave = threadIdx.x >> 6;
    const int lane = threadIdx.x & 63;
    const int gbase = (pix0 * 3) >> 2;   // float4 index of chunk start
    #pragma unroll
    for (int k = 0; k < 5; ++k) {
        const int g = k * 4 + wave;      // group id; waves 0,1 do 5, waves 2,3 do 4
        if (g < GROUPS) {
            const int u = g * 64;        // 16B-unit offset within buffer
            const float4* src;
            if (u < 384)      src = g4 + (gbase + u + lane);
            else if (u < 768) src = b4 + (gbase + (u - 384) + lane);
            else              src = f4 + (gbase + (u - 768) + lane);
            GLDS16(src, buf + u * 16);   // wave-uniform dest; HW adds lane*16
        }
    }
}

__device__ __forceinline__ float compute_chunk(
    const char* buf, const float* __restrict__ unc, int pix0,
    float threshold, int it)
{
    const float* gB = (const float*)buf;
    const float* bB = (const float*)(buf + SEG_B);
    const float* fB = (const float*)(buf + 2 * SEG_B);
    float acc = 0.0f;
    #pragma unroll
    for (int k = 0; k < CHUNK_PX / THREADS; ++k) {   // 2 pixels/thread/chunk
        const int l = threadIdx.x + k * THREADS;
        const float u = unc[pix0 + l];               // dense global, coalesced
        acc += pixel_loss(gB[3*l], gB[3*l+1], gB[3*l+2],
                          bB[3*l], bB[3*l+1], bB[3*l+2],
                          fB[3*l], fB[3*l+1], fB[3*l+2],
                          u, threshold, it);
    }
    return acc;
}

__global__ __launch_bounds__(THREADS) void loss_kernel(
    const float* __restrict__ gt, const float* __restrict__ bg,
    const float* __restrict__ fg, const float* __restrict__ unc,
    const float* __restrict__ thr_param, const int* __restrict__ iter_p,
    double* __restrict__ partials)
{
    __shared__ char lds[2][BUF_B];       // 36 KB -> 4 blocks/CU
    const int it = iter_p[0];
    const float threshold = 1.414f * (1.0f - fast_sigmoid(thr_param[0]));
    const int block_pix0 = blockIdx.x * BLOCK_PX;

    const float4* g4 = (const float4*)gt;
    const float4* b4 = (const float4*)bg;
    const float4* f4 = (const float4*)fg;

    stage_chunk(g4, b4, f4, lds[0], block_pix0);

    float local = 0.0f;
    #pragma unroll
    for (int c = 0; c < CHUNKS; ++c) {
        // Barrier drains vmcnt(0): chunk c fully staged; buffer (c+1)&1 is
        // no longer being read by any wave (its last reader was compute c-1).
        __syncthreads();
        if (c + 1 < CHUNKS)              // stage c+1 in flight under compute c
            stage_chunk(g4, b4, f4, lds[(c + 1) & 1],
                        block_pix0 + (c + 1) * CHUNK_PX);
        local += compute_chunk(lds[c & 1], unc, block_pix0 + c * CHUNK_PX,
                               threshold, it);
    }

    // 64-lane wave reduce
    #pragma unroll
    for (int off = 32; off > 0; off >>= 1)
        local += __shfl_down(local, off, 64);

    __shared__ double wsum[THREADS / 64];
    const int lane = threadIdx.x & 63;
    const int wid = threadIdx.x >> 6;
    if (lane == 0) wsum[wid] = (double)local;
    __syncthreads();
    if (threadIdx.x == 0) {
        double s = 0.0;
        #pragma unroll
        for (int w = 0; w < THREADS / 64; ++w) s += wsum[w];
        partials[blockIdx.x] = s;
    }
}

// Scalar remainder path (cold for N = 4194304; covers [start,end) pixels).
__global__ __launch_bounds__(THREADS) void tail_kernel(
    const float* __restrict__ gt, const float* __restrict__ bg,
    const float* __restrict__ fg, const float* __restrict__ unc,
    const float* __restrict__ thr_param, const int* __restrict__ iter_p,
    double* __restrict__ partials, int start, int end, int slot)
{
    const int it = iter_p[0];
    const float threshold = 1.414f * (1.0f - fast_sigmoid(thr_param[0]));
    float local = 0.0f;
    for (int p = start + (int)threadIdx.x; p < end; p += THREADS)
        local += pixel_loss(gt[3*p], gt[3*p+1], gt[3*p+2],
                            bg[3*p], bg[3*p+1], bg[3*p+2],
                            fg[3*p], fg[3*p+1], fg[3*p+2],
                            unc[p], threshold, it);
    #pragma unroll
    for (int off = 32; off > 0; off >>= 1)
        local += __shfl_down(local, off, 64);
    __shared__ double wsum[THREADS / 64];
    const int lane = threadIdx.x & 63;
    const int wid = threadIdx.x >> 6;
    if (lane == 0) wsum[wid] = (double)local;
    __syncthreads();
    if (threadIdx.x == 0) {
        double s = 0.0;
        #pragma unroll
        for (int w = 0; w < THREADS / 64; ++w) s += wsum[w];
        partials[slot] = s;
    }
}

__global__ __launch_bounds__(1024) void finalize_kernel(
    const double* __restrict__ partials, int n_part,
    const int* __restrict__ iter_p, float* __restrict__ out, int n_pix)
{
    double s = 0.0;
    for (int i = threadIdx.x; i < n_part; i += 1024)
        s += partials[i];
    #pragma unroll
    for (int off = 32; off > 0; off >>= 1)
        s += __shfl_down(s, off, 64);
    __shared__ double wsum[16];
    const int lane = threadIdx.x & 63;
    const int wid = threadIdx.x >> 6;
    if (lane == 0) wsum[wid] = s;
    __syncthreads();
    if (threadIdx.x == 0) {
        double tot = 0.0;
        #pragma unroll
        for (int w = 0; w < 16; ++w) tot += wsum[w];
        double denom = (iter_p[0] > 300) ? (double)n_pix : 3.0 * (double)n_pix;
        out[0] = (float)(tot / denom);
    }
}

extern "C" void kernel_launch(void* const* d_in, const int* in_sizes, int n_in,
                              void* d_out, int out_size, void* d_ws, size_t ws_size,
                              hipStream_t stream) {
    const float* gt  = (const float*)d_in[0];
    const float* bg  = (const float*)d_in[1];
    const float* fg  = (const float*)d_in[2];
    // d_in[3] = FG_acc : unused by reference
    const float* unc = (const float*)d_in[4];   // FG_uncertainties [N,1]
    const float* thr = (const float*)d_in[5];   // threshold_param
    // d_in[6] = steepness : unused (0.1 hard-coded in reference)
    const int*  iter = (const int*)d_in[7];

    const int n_pix = in_sizes[0] / 3;          // 4194304 -> 2048 full blocks
    int blocks = n_pix / BLOCK_PX;
    const int rem_start = blocks * BLOCK_PX;
    const int rem = n_pix - rem_start;
    int n_part = blocks + (rem > 0 ? 1 : 0);

    double* partials = (double*)d_ws;

    if ((size_t)n_part * sizeof(double) > ws_size) {
        // degenerate guard (tiny ws): single-block scalar over everything
        tail_kernel<<<1, THREADS, 0, stream>>>(gt, bg, fg, unc, thr, iter,
                                               partials, 0, n_pix, 0);
        finalize_kernel<<<1, 1024, 0, stream>>>(partials, 1, iter,
                                                (float*)d_out, n_pix);
        return;
    }

    if (blocks > 0)
        loss_kernel<<<blocks, THREADS, 0, stream>>>(gt, bg, fg, unc, thr, iter,
                                                    partials);
    if (rem > 0)
        tail_kernel<<<1, THREADS, 0, stream>>>(gt, bg, fg, unc, thr, iter,
                                               partials, rem_start, n_pix,
                                               blocks);
    finalize_kernel<<<1, 1024, 0, stream>>>(partials, n_part, iter,
                                            (float*)d_out, n_pix);
}

// Round 7
// 32.352 us; speedup vs baseline: 2.1628x; 1.0750x over previous
//
#include <hip/hip_runtime.h>
#include <math.h>

#define THREADS 1024  // 1024-thread blocks: 2 blocks/CU, 4x fewer DRAM streams/CU
#define PPT 4         // pixels per thread; block covers 4096 contiguous pixels

__device__ __forceinline__ float frcp(float x)  { return __builtin_amdgcn_rcpf(x); }
__device__ __forceinline__ float fsqrt(float x) { return __builtin_amdgcn_sqrtf(x); }

__device__ __forceinline__ float fast_sigmoid(float x) {
    return frcp(1.0f + __expf(-x));
}

// skimage-style rgb2hsv, H and V only
__device__ __forceinline__ void rgb2hv(float r, float g, float b,
                                       float& h, float& v) {
    float maxc = fmaxf(r, fmaxf(g, b));
    float minc = fminf(r, fminf(g, b));
    float delta = maxc - minc;
    float rd = frcp((delta == 0.0f) ? 1.0f : delta);
    float hh;
    if (maxc == r)      hh = (g - b) * rd;
    else if (maxc == g) hh = 2.0f + (b - r) * rd;
    else                hh = 4.0f + (r - g) * rd;
    hh = hh * (1.0f / 6.0f);
    hh = hh - floorf(hh);          // (h/6) mod 1.0
    h = (delta == 0.0f) ? 0.0f : hh;
    v = maxc;
}

__device__ __forceinline__ float pixel_loss(
    float gr, float gg, float gb,
    float br, float bgc, float bb,
    float fr, float fgc, float fb,
    float u, float threshold, int it)
{
    if (it > 300) {
        float hg, vg, hb, vb;
        rgb2hv(gr, gg, gb, hg, vg);
        rgb2hv(br, bgc, bb, hb, vb);
        float dh = hg - hb;
        float dv = vg - vb;
        float diff = fsqrt(dh * dh + dv * dv);
        float mask = fast_sigmoid((diff - threshold) * 10.0f);

        float d0 = gr - br, d1 = gg - bgc, d2 = gb - bb;
        float bg_mse = (d0 * d0 + d1 * d1 + d2 * d2) * (1.0f / 3.0f);

        float e0 = gr - fr, e1 = gg - fgc, e2 = gb - fb;
        float fg_mse = (e0 * e0 + e1 * e1 + e2 * e2) * (1.0f / 3.0f);
        float fg_perray = fg_mse * 0.5f * frcp(u * u) + __logf(u);

        return bg_mse + (fg_perray - bg_mse) * mask;
    } else {
        float d0 = gr - br, d1 = gg - bgc, d2 = gb - bb;
        return d0 * d0 + d1 * d1 + d2 * d2;  // denom = 3N in this branch
    }
}

__global__ __launch_bounds__(THREADS) void loss_kernel(
    const float* __restrict__ gt, const float* __restrict__ bg,
    const float* __restrict__ fg, const float* __restrict__ unc,
    const float* __restrict__ thr_param, const int* __restrict__ iter_p,
    double* __restrict__ partials, int n_pix)
{
    const int t = blockIdx.x * blockDim.x + threadIdx.x;
    const int p0 = t * PPT;
    const int it = iter_p[0];
    const float threshold = 1.414f * (1.0f - fast_sigmoid(thr_param[0]));

    float local = 0.0f;

    if (p0 + PPT <= n_pix) {
        const float4* g4 = (const float4*)gt + 3 * t;
        const float4* b4 = (const float4*)bg + 3 * t;
        const float4* f4 = (const float4*)fg + 3 * t;
        float4 ga = g4[0], gbv = g4[1], gc = g4[2];
        float4 ba = b4[0], bbv = b4[1], bc = b4[2];
        float4 fa = f4[0], fbv = f4[1], fc = f4[2];
        float4 u4 = *(const float4*)(unc + p0);

        float G[12] = {ga.x, ga.y, ga.z, ga.w, gbv.x, gbv.y, gbv.z, gbv.w,
                       gc.x, gc.y, gc.z, gc.w};
        float B[12] = {ba.x, ba.y, ba.z, ba.w, bbv.x, bbv.y, bbv.z, bbv.w,
                       bc.x, bc.y, bc.z, bc.w};
        float F[12] = {fa.x, fa.y, fa.z, fa.w, fbv.x, fbv.y, fbv.z, fbv.w,
                       fc.x, fc.y, fc.z, fc.w};
        float U[4] = {u4.x, u4.y, u4.z, u4.w};

        #pragma unroll
        for (int j = 0; j < PPT; ++j) {
            local += pixel_loss(G[3*j], G[3*j+1], G[3*j+2],
                                B[3*j], B[3*j+1], B[3*j+2],
                                F[3*j], F[3*j+1], F[3*j+2],
                                U[j], threshold, it);
        }
    } else if (p0 < n_pix) {
        for (int p = p0; p < n_pix; ++p) {
            local += pixel_loss(gt[3*p], gt[3*p+1], gt[3*p+2],
                                bg[3*p], bg[3*p+1], bg[3*p+2],
                                fg[3*p], fg[3*p+1], fg[3*p+2],
                                unc[p], threshold, it);
        }
    }

    // 64-lane wave reduce
    #pragma unroll
    for (int off = 32; off > 0; off >>= 1)
        local += __shfl_down(local, off, 64);

    __shared__ double wsum[THREADS / 64];
    const int lane = threadIdx.x & 63;
    const int wid = threadIdx.x >> 6;
    if (lane == 0) wsum[wid] = (double)local;
    __syncthreads();
    if (threadIdx.x == 0) {
        double s = 0.0;
        #pragma unroll
        for (int w = 0; w < THREADS / 64; ++w) s += wsum[w];
        partials[blockIdx.x] = s;   // one slot per block, no atomics
    }
}

__global__ __launch_bounds__(1024) void finalize_kernel(
    const double* __restrict__ partials, int n_part,
    const int* __restrict__ iter_p, float* __restrict__ out, int n_pix)
{
    double s = 0.0;
    for (int i = threadIdx.x; i < n_part; i += 1024)
        s += partials[i];
    #pragma unroll
    for (int off = 32; off > 0; off >>= 1)
        s += __shfl_down(s, off, 64);

    __shared__ double wsum[16];
    const int lane = threadIdx.x & 63;
    const int wid = threadIdx.x >> 6;
    if (lane == 0) wsum[wid] = s;
    __syncthreads();
    if (threadIdx.x == 0) {
        double tot = 0.0;
        #pragma unroll
        for (int w = 0; w < 16; ++w) tot += wsum[w];
        double denom = (iter_p[0] > 300) ? (double)n_pix : 3.0 * (double)n_pix;
        out[0] = (float)(tot / denom);
    }
}

extern "C" void kernel_launch(void* const* d_in, const int* in_sizes, int n_in,
                              void* d_out, int out_size, void* d_ws, size_t ws_size,
                              hipStream_t stream) {
    const float* gt  = (const float*)d_in[0];
    const float* bg  = (const float*)d_in[1];
    const float* fg  = (const float*)d_in[2];
    // d_in[3] = FG_acc : unused by reference
    const float* unc = (const float*)d_in[4];   // FG_uncertainties [N,1]
    const float* thr = (const float*)d_in[5];   // threshold_param
    // d_in[6] = steepness : unused (0.1 hard-coded in reference)
    const int*  iter = (const int*)d_in[7];

    const int n_pix = in_sizes[0] / 3;
    const int total_threads = (n_pix + PPT - 1) / PPT;
    const int blocks = (total_threads + THREADS - 1) / THREADS;  // 1024

    double* partials = (double*)d_ws;

    loss_kernel<<<blocks, THREADS, 0, stream>>>(gt, bg, fg, unc, thr, iter,
                                                partials, n_pix);
    finalize_kernel<<<1, 1024, 0, stream>>>(partials, blocks, iter,
                                            (float*)d_out, n_pix);
}